// Round 2
// baseline (527.943 us; speedup 1.0000x reference)
//
#include <hip/hip_runtime.h>

typedef __attribute__((ext_vector_type(8))) short short8v;
typedef __attribute__((ext_vector_type(4))) float float4v;
typedef __attribute__((ext_vector_type(2))) unsigned int u32x2;
typedef __attribute__((ext_vector_type(4))) unsigned int u32x4;
typedef unsigned short u16;
typedef unsigned int u32;

#define NN 4096
#define EE 32768
#define DI 128
#define DO 128

__device__ __forceinline__ u16 f2bf(float f) {
    u32 u = __builtin_bit_cast(u32, f);
    u32 r = u + 0x7fffu + ((u >> 16) & 1u);   // round-to-nearest-even
    return (u16)(r >> 16);
}
__device__ __forceinline__ u32 pack2bf(float lo, float hi) {
    return (u32)f2bf(lo) | ((u32)f2bf(hi) << 16);
}

// f32 tile [R rows x C cols] (row stride ld floats) -> LDS bf16 [R][C], XOR-swizzled
template<int R, int C>
__device__ __forceinline__ void stage_f32_bf16(char* lds, const float* src, int ld) {
    constexpr int CH = C / 8;
    constexpr int ITER = (R * CH) / 256;
#pragma unroll
    for (int it = 0; it < ITER; ++it) {
        int c = it * 256 + (int)threadIdx.x;
        int row = c / CH, col8 = c % CH;
        const float* p = src + (size_t)row * ld + col8 * 8;
        float4v v0 = *(const float4v*)p;
        float4v v1 = *(const float4v*)(p + 4);
        u32x4 w;
        w[0] = pack2bf(v0[0], v0[1]);
        w[1] = pack2bf(v0[2], v0[3]);
        w[2] = pack2bf(v1[0], v1[1]);
        w[3] = pack2bf(v1[2], v1[3]);
        int kb = col8 * 16;
        *(u32x4*)(lds + row * (C * 2) + (kb ^ ((row & 7) << 4))) = w;
    }
}

// read one 16x32 MFMA operand fragment from swizzled LDS tile (ROWB bytes/row)
template<int ROWB>
__device__ __forceinline__ short8v ldfrag(const char* base, int row16, int kk) {
    int l = (int)threadIdx.x & 63;
    int row = row16 + (l & 15);
    int kb = kk * 64 + ((l >> 4) << 4);
    return *(const short8v*)(base + row * ROWB + (kb ^ ((row & 7) << 4)));
}

// read one 16x32 MFMA operand fragment DIRECT from row-major bf16 global [row][k]
template<int LD>
__device__ __forceinline__ short8v ldfrag_g(const u16* base, int k0) {
    int l = (int)threadIdx.x & 63;
    return *(const short8v*)(base + (size_t)(l & 15) * LD + k0 + ((l >> 4) << 3));
}

// ---------- kernel 1: ATB[mo][n] = sum_i f_w[o][m*128+i] * x[n][i]  (mo = m*128+o) ----------
__global__ __launch_bounds__(256) void k1_ab(const float* __restrict__ x,
                                             const float* __restrict__ fw,
                                             u16* __restrict__ ATB) {
    __shared__ __align__(16) char lds[64 * 1024];
    char* aL = lds;              // [128 mo][128 i], ROWB 256
    char* bL = lds + 32 * 1024;  // [128 n][128 i]
    int mb = (int)blockIdx.x >> 5, nb = (int)blockIdx.x & 31;
    stage_f32_bf16<128, 128>(aL, fw + mb * 128, 2 * DI);
    stage_f32_bf16<128, 128>(bL, x + (size_t)nb * 128 * DI, DI);
    __syncthreads();
    int w = (int)threadIdx.x >> 6, l = (int)threadIdx.x & 63;
    int wr = w >> 1, wc = w & 1;
    float4v acc[4][4] = {};
#pragma unroll
    for (int kk = 0; kk < 4; ++kk) {
        short8v af[4], bf[4];
#pragma unroll
        for (int m = 0; m < 4; ++m) af[m] = ldfrag<256>(aL, wr * 64 + m * 16, kk);
#pragma unroll
        for (int n2 = 0; n2 < 4; ++n2) bf[n2] = ldfrag<256>(bL, wc * 64 + n2 * 16, kk);
#pragma unroll
        for (int m = 0; m < 4; ++m)
#pragma unroll
            for (int n2 = 0; n2 < 4; ++n2)
                acc[m][n2] = __builtin_amdgcn_mfma_f32_16x16x32_bf16(af[m], bf[n2], acc[m][n2], 0, 0, 0);
    }
#pragma unroll
    for (int m = 0; m < 4; ++m)
#pragma unroll
        for (int n2 = 0; n2 < 4; ++n2)
#pragma unroll
            for (int r = 0; r < 4; ++r) {
                int mo = mb * 128 + wr * 64 + m * 16 + ((l >> 4) << 2) + r;
                int n  = nb * 128 + wc * 64 + n2 * 16 + (l & 15);
                ATB[(size_t)mo * NN + n] = f2bf(acc[m][n2][r]);
            }
}

// ---------- kernel 2: YT[o][e] = relu(sum_n ATB[0][o][n]*src[n][e] + ATB[1][o][n]*tgt[n][e] + fb[o]) ----------
// e-tile 32, grid 1024. A-frags direct from L2-resident ATB; src/tgt transposed tiles
// double-buffered in LDS with reg-prefetch; ONE barrier per K-step.
__global__ __launch_bounds__(256, 4) void k2_y(const float* __restrict__ src,
                                               const float* __restrict__ tgt,
                                               const u16* __restrict__ ATB,
                                               const float* __restrict__ fb,
                                               u16* __restrict__ YT) {
    __shared__ __align__(16) char lds[16 * 1024]; // [buf2][mat2][32 e][64 n] bf16, swizzled
    const int eb = (int)blockIdx.x * 32;
    const int t = (int)threadIdx.x, w = t >> 6, l = t & 63;
    // staging: threads 0-127 -> src, 128-255 -> tgt; each thread 4 rows x 4 e (f32)
    const int smat = t >> 7, tt = t & 127, eq = tt & 7, nq = tt >> 3;
    const float* sbase = (smat ? tgt : src) + (size_t)(nq * 4) * EE + eb + eq * 4;
    float4v pn0, pn1, pn2, pn3;
    auto loadT = [&](int n0) {
        const float* p = sbase + (size_t)n0 * EE;
        pn0 = *(const float4v*)p;
        pn1 = *(const float4v*)(p + EE);
        pn2 = *(const float4v*)(p + 2 * EE);
        pn3 = *(const float4v*)(p + 3 * EE);
    };
    auto writeT = [&](char* buf) {
        char* L = buf + smat * 4096;
#pragma unroll
        for (int j = 0; j < 4; ++j) {
            int e = eq * 4 + j;
            u32x2 w2;
            w2[0] = pack2bf(pn0[j], pn1[j]);
            w2[1] = pack2bf(pn2[j], pn3[j]);
            *(u32x2*)(L + e * 128 + ((nq * 8) ^ ((e & 7) << 4))) = w2;
        }
    };
    loadT(0);
    writeT(lds);
    __syncthreads();
    float4v acc[2][2] = {};
    int p = 0;
    for (int ks = 0; ks < 64; ++ks) {
        const bool more = ks < 63;
        if (more) loadT((ks + 1) * 64);          // prefetch next tile (HBM) into regs
        const int n0 = ks * 64;
        short8v af[2][2][2], bfr[2][2][2];
#pragma unroll
        for (int mat = 0; mat < 2; ++mat)
#pragma unroll
            for (int kk = 0; kk < 2; ++kk) {
#pragma unroll
                for (int m = 0; m < 2; ++m)
                    af[mat][kk][m] = ldfrag_g<NN>(ATB + (size_t)(mat * 128 + w * 32 + m * 16) * NN,
                                                  n0 + kk * 32);
#pragma unroll
                for (int n2 = 0; n2 < 2; ++n2)
                    bfr[mat][kk][n2] = ldfrag<128>(lds + p * 8192 + mat * 4096, n2 * 16, kk);
            }
#pragma unroll
        for (int mat = 0; mat < 2; ++mat)
#pragma unroll
            for (int kk = 0; kk < 2; ++kk)
#pragma unroll
                for (int m = 0; m < 2; ++m)
#pragma unroll
                    for (int n2 = 0; n2 < 2; ++n2)
                        acc[m][n2] = __builtin_amdgcn_mfma_f32_16x16x32_bf16(
                            af[mat][kk][m], bfr[mat][kk][n2], acc[m][n2], 0, 0, 0);
        if (more) {
            writeT(lds + (p ^ 1) * 8192);        // vmcnt wait happens here (compiler)
            __syncthreads();
            p ^= 1;
        }
    }
#pragma unroll
    for (int m = 0; m < 2; ++m)
#pragma unroll
        for (int n2 = 0; n2 < 2; ++n2)
#pragma unroll
            for (int r = 0; r < 4; ++r) {
                int o = w * 32 + m * 16 + ((l >> 4) << 2) + r;
                int e = eb + n2 * 16 + (l & 15);
                float v = acc[m][n2][r] + fb[o];
                v = v > 0.f ? v : 0.f;
                YT[(size_t)o * EE + e] = f2bf(v);
            }
}

// ---------- kernel 3: part[kc][n][o] = sum_{e in chunk kc} tgt[n][e] * YT[o][e] ----------
// 16 e-chunks of 2048, grid 1024. B-frags direct from L3-resident YT;
// tgt tiles double-buffered in LDS with reg-prefetch; ONE barrier per K-step.
__global__ __launch_bounds__(256, 4) void k3_part(const float* __restrict__ tgt,
                                                  const u16* __restrict__ YT,
                                                  float* __restrict__ part) {
    __shared__ __align__(16) char lds[16 * 1024]; // [buf2][64 n][64 e] bf16, swizzled
    const int mb = (int)blockIdx.x & 63, kc = (int)blockIdx.x >> 6;
    const int e0 = kc * 2048;
    const int t = (int)threadIdx.x, w = t >> 6, l = t & 63;
    const int wr = w >> 1, wc = w & 1;
    // staging: each thread 2 rows (srow, srow+32) x 8 e (f32)
    const int srow = t >> 3, scol = (t & 7) * 8;
    const float* sbase = tgt + (size_t)(mb * 64 + srow) * EE + e0 + scol;
    float4v pa0, pa1, pb0, pb1;
    auto loadT = [&](int ec) {
        const float* p = sbase + ec * 64;
        pa0 = *(const float4v*)p;
        pa1 = *(const float4v*)(p + 4);
        const float* q = p + (size_t)32 * EE;
        pb0 = *(const float4v*)q;
        pb1 = *(const float4v*)(q + 4);
    };
    auto writeT = [&](char* buf) {
        u32x4 w4;
        w4[0] = pack2bf(pa0[0], pa0[1]); w4[1] = pack2bf(pa0[2], pa0[3]);
        w4[2] = pack2bf(pa1[0], pa1[1]); w4[3] = pack2bf(pa1[2], pa1[3]);
        *(u32x4*)(buf + srow * 128 + ((scol * 2) ^ ((srow & 7) << 4))) = w4;
        w4[0] = pack2bf(pb0[0], pb0[1]); w4[1] = pack2bf(pb0[2], pb0[3]);
        w4[2] = pack2bf(pb1[0], pb1[1]); w4[3] = pack2bf(pb1[2], pb1[3]);
        const int r2 = srow + 32;
        *(u32x4*)(buf + r2 * 128 + ((scol * 2) ^ ((r2 & 7) << 4))) = w4;
    };
    loadT(0);
    writeT(lds);
    __syncthreads();
    float4v acc[2][4] = {};
    int p = 0;
    for (int es = 0; es < 32; ++es) {
        const bool more = es < 31;
        if (more) loadT(es + 1);                 // prefetch next tgt tile (HBM)
        short8v af[2][2], bfr[2][4];
#pragma unroll
        for (int kk = 0; kk < 2; ++kk) {
#pragma unroll
            for (int n2 = 0; n2 < 4; ++n2)
                bfr[kk][n2] = ldfrag_g<EE>(YT + (size_t)(wc * 64 + n2 * 16) * EE,
                                           e0 + es * 64 + kk * 32);
#pragma unroll
            for (int m = 0; m < 2; ++m)
                af[kk][m] = ldfrag<128>(lds + p * 8192, wr * 32 + m * 16, kk);
        }
#pragma unroll
        for (int kk = 0; kk < 2; ++kk)
#pragma unroll
            for (int m = 0; m < 2; ++m)
#pragma unroll
                for (int n2 = 0; n2 < 4; ++n2)
                    acc[m][n2] = __builtin_amdgcn_mfma_f32_16x16x32_bf16(
                        af[kk][m], bfr[kk][n2], acc[m][n2], 0, 0, 0);
        if (more) {
            writeT(lds + (p ^ 1) * 8192);
            __syncthreads();
            p ^= 1;
        }
    }
#pragma unroll
    for (int m = 0; m < 2; ++m)
#pragma unroll
        for (int n2 = 0; n2 < 4; ++n2)
#pragma unroll
            for (int r = 0; r < 4; ++r) {
                int n = mb * 64 + wr * 32 + m * 16 + ((l >> 4) << 2) + r;
                int o = wc * 64 + n2 * 16 + (l & 15);
                part[((size_t)kc * NN + n) * DO + o] = acc[m][n2][r];
            }
}

// ---------- kernel 4: out = sum_kc part[kc] ----------
__global__ __launch_bounds__(256) void k4_red(const float* __restrict__ part,
                                              float* __restrict__ out) {
    size_t i = ((size_t)blockIdx.x * 256 + threadIdx.x) * 4;
    float4v s = {0.f, 0.f, 0.f, 0.f};
#pragma unroll
    for (int kc = 0; kc < 16; ++kc)
        s += *(const float4v*)(part + (size_t)kc * NN * DO + i);
    *(float4v*)(out + i) = s;
}

extern "C" void kernel_launch(void* const* d_in, const int* in_sizes, int n_in,
                              void* d_out, int out_size, void* d_ws, size_t ws_size,
                              hipStream_t stream) {
    const float* x   = (const float*)d_in[0];
    const float* src = (const float*)d_in[1];
    const float* tgt = (const float*)d_in[2];
    const float* fw  = (const float*)d_in[3];
    const float* fb  = (const float*)d_in[4];
    float* out = (float*)d_out;

    char* ws = (char*)d_ws;
    u16*   ATB  = (u16*)ws;                                    //  2 MB: [256][4096] bf16
    u16*   YT   = (u16*)(ws + (size_t)2 * 1024 * 1024);        //  8 MB: [128][32768] bf16
    float* PART = (float*)(ws + (size_t)10 * 1024 * 1024);     // 32 MB: [16][4096][128] f32

    k1_ab  <<<64,   256, 0, stream>>>(x, fw, ATB);
    k2_y   <<<1024, 256, 0, stream>>>(src, tgt, ATB, fb, YT);
    k3_part<<<1024, 256, 0, stream>>>(tgt, YT, PART);
    k4_red <<<512,  256, 0, stream>>>(PART, out);
}